// Round 11
// baseline (159.530 us; speedup 1.0000x reference)
//
#include <hip/hip_runtime.h>

// Problem constants
#define BB   4
#define SEQ  2048
#define EMB  512
#define NH   8
#define HD   64
// SCALE = HD^-0.5 = 0.125; folded with log2(e) into Q at qkv epilogue:
#define QSCALE 0.18033688011f   // 0.125 * log2(e)

typedef __bf16 bf16x8 __attribute__((ext_vector_type(8)));
typedef float  f32x4  __attribute__((ext_vector_type(4)));

__device__ __forceinline__ short f2bf(float f) {
  union { float f; unsigned u; } v; v.f = f;
  unsigned r = v.u + 0x7fffu + ((v.u >> 16) & 1u);   // RNE
  return (short)(r >> 16);
}

// packed fp32x2 -> bf16x2 (RNE), hardware on gfx950
__device__ __forceinline__ unsigned pk_bf16(float a, float b) {
#if __has_builtin(__builtin_amdgcn_cvt_pk_bf16_f32)
  typedef __bf16 bf16v2 __attribute__((ext_vector_type(2)));
  union { bf16v2 v; unsigned u; } cv;
  cv.v = __builtin_amdgcn_cvt_pk_bf16_f32(a, b);
  return cv.u;
#else
  return (unsigned)(unsigned short)f2bf(a) | ((unsigned)(unsigned short)f2bf(b) << 16);
#endif
}

__device__ __forceinline__ float fexp2(float x) {
#if __has_builtin(__builtin_amdgcn_exp2f)
  return __builtin_amdgcn_exp2f(x);
#else
  return exp2f(x);
#endif
}

__device__ __forceinline__ void gl_lds16(const void* g, void* l) {
  __builtin_amdgcn_global_load_lds(
      (const __attribute__((address_space(1))) unsigned int*)g,
      (__attribute__((address_space(3))) unsigned int*)l, 16, 0, 0);
}

// quad-axis redistribution for P: (a,b) = (even-kt, odd-kt) packed pair.
// After the two swaps (gfx950 VALU cross-lane, no LDS pipe) the words land in
// exactly the PV A-fragment layout (verified round 4: absmax unchanged, conflicts 0).
__device__ __forceinline__ void quad_redist(unsigned &a, unsigned &b) {
  asm volatile("v_permlane32_swap_b32 %0, %1" : "+v"(a), "+v"(b));
  asm volatile("v_permlane16_swap_b32 %0, %1" : "+v"(a), "+v"(b));
}

// ---------------------------------------------------------------- fused casts
// x: 1048576 float4 groups; w_qkv: 196608; w_out: 65536. total 1310720 -> 5120 blocks
__global__ __launch_bounds__(256) void cast_all(const float* __restrict__ x,
                                                const float* __restrict__ wq,
                                                const float* __restrict__ wo,
                                                short* __restrict__ xb,
                                                short* __restrict__ wqb,
                                                short* __restrict__ wob) {
  int i = blockIdx.x * 256 + threadIdx.x;
  const float* src; short* dst; int off;
  if (i < 1048576)      { src = x;  dst = xb;  off = i; }
  else if (i < 1245184) { src = wq; dst = wqb; off = i - 1048576; }
  else                  { src = wo; dst = wob; off = i - 1245184; }
  float4 v = ((const float4*)src)[off];
  uint2 o; o.x = pk_bf16(v.x, v.y); o.y = pk_bf16(v.z, v.w);
  *(uint2*)&dst[off * 4] = o;
}

// ---------------------------------------------------------------- QKV projection
// v5: BK=64 — halve the barrier-period count (16 -> 8). Round-10 showed occupancy
//   up but time flat: period cost (~1.8us/period at attn's measured rate) dominates,
//   so fewer/fatter periods is the lever. 128x128 tile, 512 thr (8 waves, 4m x 2f,
//   wave 32x64, acc[2][4]); dbuf LDS = 64KB -> 2 blocks/CU (16 waves/CU).
// Swizzle (64-elem rows, 8 x 16B chunks — round-8/attn pattern verbatim):
//   store chunk c of row holds source chunk c^(row&7); read chunk (kk*4+quad)^(col&7);
//   read rows = 16k+col so row&7 == col&7 within the XOR -> recovers source chunk kk*4+quad.
__global__ __launch_bounds__(512) void qkv_gemm(const short* __restrict__ A,
                                                const short* __restrict__ W,
                                                const float* __restrict__ bias,
                                                short* __restrict__ qo,
                                                short* __restrict__ ko,
                                                short* __restrict__ vto) {
  __shared__ __align__(16) short As0[128 * 64];   // 16KB each, 64KB total
  __shared__ __align__(16) short Bs0[128 * 64];
  __shared__ __align__(16) short As1[128 * 64];
  __shared__ __align__(16) short Bs1[128 * 64];
  const int tid  = threadIdx.x;
  const int lane = tid & 63, wave = tid >> 6;
  const int wm = wave >> 1, wf = wave & 1;
  const int col = lane & 15, quad = lane >> 4;
  const int m0 = blockIdx.x * 128, f0 = blockIdx.y * 128;

  // staging: 2 issues per operand per step; slot = rd*512+tid -> 128 rows x 8 chunks
  const short* aSrc[2]; const short* wSrc[2];
#pragma unroll
  for (int rd = 0; rd < 2; ++rd) {
    int slot = rd * 512 + tid;
    int row  = slot >> 3;
    int cb   = (slot & 7) ^ (row & 7);
    aSrc[rd] = A + (size_t)(m0 + row) * 512 + cb * 8;
    wSrc[rd] = W + (size_t)(f0 + row) * 512 + cb * 8;
  }
  // fragment LDS element offsets (row*64 + readchunk*8)
  int aOff[2][2], bOff[2][4];
#pragma unroll
  for (int kk = 0; kk < 2; ++kk) {
#pragma unroll
    for (int i = 0; i < 2; ++i)
      aOff[kk][i] = (wm * 32 + i * 16 + col) * 64 + (((kk * 4 + quad) ^ (col & 7)) * 8);
#pragma unroll
    for (int j = 0; j < 4; ++j)
      bOff[kk][j] = (wf * 64 + j * 16 + col) * 64 + (((kk * 4 + quad) ^ (col & 7)) * 8);
  }

  f32x4 acc[2][4];
#pragma unroll
  for (int i = 0; i < 2; ++i)
#pragma unroll
    for (int j = 0; j < 4; ++j)
#pragma unroll
      for (int r = 0; r < 4; ++r) acc[i][j][r] = 0.f;

#define QSTAGE(BUFA, BUFB, KS)                                               \
  {                                                                          \
    const int ko_ = (KS) * 64;                                               \
    _Pragma("unroll")                                                        \
    for (int rd = 0; rd < 2; ++rd) {                                         \
      gl_lds16(aSrc[rd] + ko_, (char*)(BUFA) + rd * 8192 + wave * 1024);     \
      gl_lds16(wSrc[rd] + ko_, (char*)(BUFB) + rd * 8192 + wave * 1024);     \
    }                                                                        \
  }

  auto qcompute = [&](const short* As, const short* Bs) {
#pragma unroll
    for (int kk = 0; kk < 2; ++kk) {
      bf16x8 af[2], bw[4];
#pragma unroll
      for (int i = 0; i < 2; ++i) af[i] = *(const bf16x8*)&As[aOff[kk][i]];
#pragma unroll
      for (int j = 0; j < 4; ++j) bw[j] = *(const bf16x8*)&Bs[bOff[kk][j]];
#pragma unroll
      for (int i = 0; i < 2; ++i)
#pragma unroll
        for (int j = 0; j < 4; ++j)
          acc[i][j] = __builtin_amdgcn_mfma_f32_16x16x32_bf16(af[i], bw[j], acc[i][j], 0, 0, 0);
    }
  };

  // prologue
  QSTAGE(As0, Bs0, 0);
  __syncthreads();
  for (int t = 0; t < 8; t += 2) {
    QSTAGE(As1, Bs1, t + 1);          // t+1 <= 7 always
    qcompute(As0, Bs0);
    __syncthreads();                  // drains t+1 loads (flew during compute)
    QSTAGE(As0, Bs0, (t + 2) & 7);    // last iter wraps to 0 (harmless re-read, avoids OOB)
    qcompute(As1, Bs1);
    __syncthreads();
  }
#undef QSTAGE

  // epilogue: C/D layout row = quad*4+r, col = lane&15
#pragma unroll
  for (int j = 0; j < 4; ++j) {
    const int f = f0 + wf * 64 + j * 16 + col;
    const float bv = bias[f];
    const int sIdx = f >> 9;          // 0=Q 1=K 2=V (uniform per wave: 64-wide span)
    const int h = (f >> 6) & 7;
    const int d = f & 63;
#pragma unroll
    for (int i = 0; i < 2; ++i) {
      const int mbase = m0 + wm * 32 + i * 16 + quad * 4;
      const int b = mbase >> 11;
      const int n = mbase & 2047;
      const size_t bh = (size_t)(b * NH + h);
      if (sIdx == 2) {
        uint2 pk;
        pk.x = pk_bf16(acc[i][j][0] + bv, acc[i][j][1] + bv);
        pk.y = pk_bf16(acc[i][j][2] + bv, acc[i][j][3] + bv);
        *(uint2*)&vto[(bh * HD + d) * SEQ + n] = pk;     // V^T: (bh, d, n)
      } else if (sIdx == 0) {
#pragma unroll
        for (int r = 0; r < 4; ++r)
          qo[(bh * SEQ + n + r) * HD + d] = f2bf((acc[i][j][r] + bv) * QSCALE);
      } else {
#pragma unroll
        for (int r = 0; r < 4; ++r)
          ko[(bh * SEQ + n + r) * HD + d] = f2bf(acc[i][j][r] + bv);
      }
    }
  }
}

// ---------------------------------------------------------------- flash attention v7 (round-4/8/10 best: ~56-58us)
// grid = 512 x 512 threads: bh = blk&31, qtile = blk>>5 (128 q/block, 8 waves x 16 q)
// K,V: double-buffered LDS (XOR-swizzled, global_load_lds), 1 barrier/tile.
// P: in-register redistribution (permlane16/32_swap), no LDS round-trip.
// S^T operand-swap; fixed-max softmax (exp2, scale pre-folded into Q).
__global__ __launch_bounds__(512) void attn_kernel(const short* __restrict__ q,
                                                   const short* __restrict__ k,
                                                   const short* __restrict__ vt,
                                                   short* __restrict__ o) {
  __shared__ __align__(16) short Ks0[64 * 64];       // XOR-swizzled
  __shared__ __align__(16) short Vs0[64 * 64];
  __shared__ __align__(16) short Ks1[64 * 64];
  __shared__ __align__(16) short Vs1[64 * 64];

  const int tid  = threadIdx.x;
  const int lane = tid & 63, wave = tid >> 6;
  const int col = lane & 15, quad = lane >> 4;
  const int bh = blockIdx.x & 31;
  const int q0 = (blockIdx.x >> 5) * 128;
  const size_t bhBase = (size_t)bh * SEQ * HD;

  // Q fragments (B-operand): lane holds Q'[q=col][d = ks*32 + quad*8 + j]
  bf16x8 qf[2];
#pragma unroll
  for (int ks = 0; ks < 2; ++ks)
    qf[ks] = *(const bf16x8*)&q[bhBase +
        (size_t)(q0 + wave * 16 + col) * HD + ks * 32 + quad * 8];

  // staging: 512 threads x 16B = one 64x64 bf16 tile per issue
  const int row = tid >> 3, cb = (tid & 7) ^ (row & 7);
  const short* ksrc = k  + bhBase + (size_t)row * HD  + cb * 8;
  const short* vsrc = vt + bhBase + (size_t)row * SEQ + cb * 8;
  char* const ldsK0 = (char*)Ks0 + wave * 1024;
  char* const ldsV0 = (char*)Vs0 + wave * 1024;
  char* const ldsK1 = (char*)Ks1 + wave * 1024;
  char* const ldsV1 = (char*)Vs1 + wave * 1024;

  f32x4 oacc[4];
#pragma unroll
  for (int nt = 0; nt < 4; ++nt)
#pragma unroll
    for (int r = 0; r < 4; ++r) oacc[nt][r] = 0.f;
  float lsum = 0.f;

  auto compute = [&](const short* KB, const short* VB) {
    // S^T = K Q'^T : C[m=key][n=q]; lane holds S^T[key=kt*16+quad*4+r][q=col]
    f32x4 sacc[4];
#pragma unroll
    for (int kt = 0; kt < 4; ++kt)
#pragma unroll
      for (int r = 0; r < 4; ++r) sacc[kt][r] = 0.f;
#pragma unroll
    for (int ks = 0; ks < 2; ++ks)
#pragma unroll
      for (int kt = 0; kt < 4; ++kt) {
        bf16x8 kf = *(const bf16x8*)&KB[(kt * 16 + col) * 64 +
                                        (((ks * 4 + quad) ^ (col & 7)) * 8)];
        sacc[kt] = __builtin_amdgcn_mfma_f32_16x16x32_bf16(kf, qf[ks], sacc[kt], 0, 0, 0);
      }

    // p = exp2(s') (scale pre-folded into Q'), partial row-sums, pack pairs
    unsigned u[4][2];
#pragma unroll
    for (int kt = 0; kt < 4; ++kt) {
      float p0 = fexp2(sacc[kt][0]);
      float p1 = fexp2(sacc[kt][1]);
      float p2 = fexp2(sacc[kt][2]);
      float p3 = fexp2(sacc[kt][3]);
      lsum += (p0 + p1) + (p2 + p3);
      u[kt][0] = pk_bf16(p0, p1);   // keys kt*16+quad*4+{0,1}
      u[kt][1] = pk_bf16(p2, p3);   // keys kt*16+quad*4+{2,3}
    }

    // in-register quad redistribution -> PV A-fragments
    // pf[ks2] elem j = P[q=col][key = ks2*32 + quad*8 + j]
    union { unsigned w[4]; bf16x8 v; } pf0, pf1;
    {
      unsigned a, b;
      a = u[0][0]; b = u[1][0]; quad_redist(a, b); pf0.w[0] = a; pf0.w[2] = b;
      a = u[0][1]; b = u[1][1]; quad_redist(a, b); pf0.w[1] = a; pf0.w[3] = b;
      a = u[2][0]; b = u[3][0]; quad_redist(a, b); pf1.w[0] = a; pf1.w[2] = b;
      a = u[2][1]; b = u[3][1]; quad_redist(a, b); pf1.w[1] = a; pf1.w[3] = b;
    }

    // O += P V   (A = P[q][key] in registers, B = V^T[d][key] from LDS)
#pragma unroll
    for (int nt = 0; nt < 4; ++nt) {
      bf16x8 vf0 = *(const bf16x8*)&VB[(nt * 16 + col) * 64 +
                                       ((quad ^ (col & 7)) * 8)];
      oacc[nt] = __builtin_amdgcn_mfma_f32_16x16x32_bf16(pf0.v, vf0, oacc[nt], 0, 0, 0);
      bf16x8 vf1 = *(const bf16x8*)&VB[(nt * 16 + col) * 64 +
                                       (((4 + quad) ^ (col & 7)) * 8)];
      oacc[nt] = __builtin_amdgcn_mfma_f32_16x16x32_bf16(pf1.v, vf1, oacc[nt], 0, 0, 0);
    }
  };

  // prologue: stage tile 0
  gl_lds16(ksrc, ldsK0); gl_lds16(vsrc, ldsV0);
  ksrc += 64 * HD; vsrc += 64;
  __syncthreads();

  for (int t = 0; t < 32; t += 2) {
    // stage tile t+1 into buf1; compute tile t from buf0
    gl_lds16(ksrc, ldsK1); gl_lds16(vsrc, ldsV1);
    ksrc += 64 * HD; vsrc += 64;
    compute(Ks0, Vs0);
    __syncthreads();                 // drains t+1 loads (flew during compute)
    // stage tile t+2 into buf0; compute tile t+1 from buf1
    // (final iteration prefetches one tile past the end — lands in the
    //  adjacent workspace arrays, in-bounds of d_ws, never consumed)
    gl_lds16(ksrc, ldsK0); gl_lds16(vsrc, ldsV0);
    ksrc += 64 * HD; vsrc += 64;
    compute(Ks1, Vs1);
    __syncthreads();
  }

  // final row-sum reduce across quads (lanes sharing col hold partials)
  lsum += __shfl_xor(lsum, 16);
  lsum += __shfl_xor(lsum, 32);

  const int b = bh >> 3, h = bh & 7;
#pragma unroll
  for (int r = 0; r < 4; ++r) {
    const float rl = 1.0f / __shfl(lsum, quad * 4 + r);  // sum for q=quad*4+r lives at lane col==q
    const int n = q0 + wave * 16 + quad * 4 + r;
#pragma unroll
    for (int nt = 0; nt < 4; ++nt)
      o[((size_t)(b * SEQ + n)) * EMB + h * HD + nt * 16 + col] = f2bf(oacc[nt][r] * rl);
  }
}

// ---------------------------------------------------------------- out projection
// v5: BK=64, 8 periods. 64x128 tile, 512 thr (8 waves as 2m x 4f, wave 32x32,
// acc[2][2]); dbuf LDS = 48KB -> 3 blocks/CU (24 waves/CU). Same swizzle as qkv v5.
__global__ __launch_bounds__(512) void proj_gemm(const short* __restrict__ A,
                                                 const short* __restrict__ W,
                                                 const float* __restrict__ bias,
                                                 float* __restrict__ out) {
  __shared__ __align__(16) short As0[64 * 64];    // 8KB
  __shared__ __align__(16) short Bs0[128 * 64];   // 16KB
  __shared__ __align__(16) short As1[64 * 64];
  __shared__ __align__(16) short Bs1[128 * 64];
  const int tid  = threadIdx.x;
  const int lane = tid & 63, wave = tid >> 6;
  const int wm = wave >> 2, wf = wave & 3;
  const int col = lane & 15, quad = lane >> 4;
  const int m0 = blockIdx.x * 64, f0 = blockIdx.y * 128;

  // A staging: one issue (512 slots = 64 rows x 8 chunks)
  const int arow = tid >> 3, acb = (tid & 7) ^ (arow & 7);
  const short* aSrc = A + (size_t)(m0 + arow) * 512 + acb * 8;
  // B staging: two issues (128 rows x 8 chunks)
  const short* wSrc[2];
#pragma unroll
  for (int rd = 0; rd < 2; ++rd) {
    int slot = rd * 512 + tid;
    int row  = slot >> 3;
    int cb   = (slot & 7) ^ (row & 7);
    wSrc[rd] = W + (size_t)(f0 + row) * 512 + cb * 8;
  }
  int aOff[2][2], bOff[2][2];
#pragma unroll
  for (int kk = 0; kk < 2; ++kk) {
#pragma unroll
    for (int i = 0; i < 2; ++i)
      aOff[kk][i] = (wm * 32 + i * 16 + col) * 64 + (((kk * 4 + quad) ^ (col & 7)) * 8);
#pragma unroll
    for (int j = 0; j < 2; ++j)
      bOff[kk][j] = (wf * 32 + j * 16 + col) * 64 + (((kk * 4 + quad) ^ (col & 7)) * 8);
  }

  f32x4 acc[2][2];
#pragma unroll
  for (int i = 0; i < 2; ++i)
#pragma unroll
    for (int j = 0; j < 2; ++j)
#pragma unroll
      for (int r = 0; r < 4; ++r) acc[i][j][r] = 0.f;

#define PSTAGE(BUFA, BUFB, KS)                                               \
  {                                                                          \
    const int ko_ = (KS) * 64;                                               \
    gl_lds16(aSrc + ko_, (char*)(BUFA) + wave * 1024);                       \
    _Pragma("unroll")                                                        \
    for (int rd = 0; rd < 2; ++rd)                                           \
      gl_lds16(wSrc[rd] + ko_, (char*)(BUFB) + rd * 8192 + wave * 1024);     \
  }

  auto pcompute = [&](const short* As, const short* Bs) {
#pragma unroll
    for (int kk = 0; kk < 2; ++kk) {
      bf16x8 af[2], bw[2];
#pragma unroll
      for (int i = 0; i < 2; ++i) af[i] = *(const bf16x8*)&As[aOff[kk][i]];
#pragma unroll
      for (int j = 0; j < 2; ++j) bw[j] = *(const bf16x8*)&Bs[bOff[kk][j]];
#pragma unroll
      for (int i = 0; i < 2; ++i)
#pragma unroll
        for (int j = 0; j < 2; ++j)
          acc[i][j] = __builtin_amdgcn_mfma_f32_16x16x32_bf16(af[i], bw[j], acc[i][j], 0, 0, 0);
    }
  };

  PSTAGE(As0, Bs0, 0);
  __syncthreads();
  for (int t = 0; t < 8; t += 2) {
    PSTAGE(As1, Bs1, t + 1);
    pcompute(As0, Bs0);
    __syncthreads();
    PSTAGE(As0, Bs0, (t + 2) & 7);    // wrap on last iter (harmless, avoids OOB)
    pcompute(As1, Bs1);
    __syncthreads();
  }
#undef PSTAGE

#pragma unroll
  for (int j = 0; j < 2; ++j) {
    const int f = f0 + wf * 32 + j * 16 + col;
    const float bv = bias[f];
#pragma unroll
    for (int i = 0; i < 2; ++i) {
      const int mbase = m0 + wm * 32 + i * 16 + quad * 4;
#pragma unroll
      for (int r = 0; r < 4; ++r)
        out[(size_t)(mbase + r) * 512 + f] = acc[i][j][r] + bv;
    }
  }
}

// ---------------------------------------------------------------- launch
extern "C" void kernel_launch(void* const* d_in, const int* in_sizes, int n_in,
                              void* d_out, int out_size, void* d_ws, size_t ws_size,
                              hipStream_t stream) {
  (void)in_sizes; (void)n_in; (void)out_size; (void)ws_size;
  const float* x     = (const float*)d_in[0];
  const float* w_qkv = (const float*)d_in[1];
  const float* b_qkv = (const float*)d_in[2];
  const float* w_out = (const float*)d_in[3];
  const float* b_out = (const float*)d_in[4];
  float* out = (float*)d_out;

  char* ws = (char*)d_ws;
  short* xb    = (short*)(ws + 0);         // 8,388,608
  short* wqkvb = (short*)(ws + 8388608);   // 1,572,864
  short* woutb = (short*)(ws + 9961472);   //   524,288
  short* qb    = (short*)(ws + 10485760);  // 8,388,608  (b,h,n,d)  pre-scaled by QSCALE
  short* kb    = (short*)(ws + 18874368);  // 8,388,608  (b,h,n,d)
  short* vtb   = (short*)(ws + 27262976);  // 8,388,608  (b,h,d,n)
  short* ob    = (short*)(ws + 35651584);  // 8,388,608  (b,n,e)

  cast_all<<<5120, 256, 0, stream>>>(x, w_qkv, w_out, xb, wqkvb, woutb);
  qkv_gemm<<<dim3(64, 12), 512, 0, stream>>>(xb, wqkvb, b_qkv, qb, kb, vtb);
  attn_kernel<<<512, 512, 0, stream>>>(qb, kb, vtb, ob);
  proj_gemm<<<dim3(128, 4), 512, 0, stream>>>(ob, woutb, b_out, out);
}

// Round 12
// 155.133 us; speedup vs baseline: 1.0283x; 1.0283x over previous
//
#include <hip/hip_runtime.h>

// Problem constants
#define BB   4
#define SEQ  2048
#define EMB  512
#define NH   8
#define HD   64
// SCALE = HD^-0.5 = 0.125; folded with log2(e) into Q at qkv epilogue:
#define QSCALE 0.18033688011f   // 0.125 * log2(e)

typedef __bf16 bf16x8 __attribute__((ext_vector_type(8)));
typedef float  f32x4  __attribute__((ext_vector_type(4)));

__device__ __forceinline__ short f2bf(float f) {
  union { float f; unsigned u; } v; v.f = f;
  unsigned r = v.u + 0x7fffu + ((v.u >> 16) & 1u);   // RNE
  return (short)(r >> 16);
}

// packed fp32x2 -> bf16x2 (RNE), hardware on gfx950
__device__ __forceinline__ unsigned pk_bf16(float a, float b) {
#if __has_builtin(__builtin_amdgcn_cvt_pk_bf16_f32)
  typedef __bf16 bf16v2 __attribute__((ext_vector_type(2)));
  union { bf16v2 v; unsigned u; } cv;
  cv.v = __builtin_amdgcn_cvt_pk_bf16_f32(a, b);
  return cv.u;
#else
  return (unsigned)(unsigned short)f2bf(a) | ((unsigned)(unsigned short)f2bf(b) << 16);
#endif
}

__device__ __forceinline__ float fexp2(float x) {
#if __has_builtin(__builtin_amdgcn_exp2f)
  return __builtin_amdgcn_exp2f(x);
#else
  return exp2f(x);
#endif
}

__device__ __forceinline__ void gl_lds16(const void* g, void* l) {
  __builtin_amdgcn_global_load_lds(
      (const __attribute__((address_space(1))) unsigned int*)g,
      (__attribute__((address_space(3))) unsigned int*)l, 16, 0, 0);
}

// quad-axis redistribution for P: (a,b) = (even-kt, odd-kt) packed pair.
// After the two swaps (gfx950 VALU cross-lane, no LDS pipe) the words land in
// exactly the PV A-fragment layout (verified round 4: absmax unchanged, conflicts 0).
__device__ __forceinline__ void quad_redist(unsigned &a, unsigned &b) {
  asm volatile("v_permlane32_swap_b32 %0, %1" : "+v"(a), "+v"(b));
  asm volatile("v_permlane16_swap_b32 %0, %1" : "+v"(a), "+v"(b));
}

// ---------------------------------------------------------------- fused casts
// x: 1048576 float4 groups; w_qkv: 196608; w_out: 65536. total 1310720 -> 5120 blocks
__global__ __launch_bounds__(256) void cast_all(const float* __restrict__ x,
                                                const float* __restrict__ wq,
                                                const float* __restrict__ wo,
                                                short* __restrict__ xb,
                                                short* __restrict__ wqb,
                                                short* __restrict__ wob) {
  int i = blockIdx.x * 256 + threadIdx.x;
  const float* src; short* dst; int off;
  if (i < 1048576)      { src = x;  dst = xb;  off = i; }
  else if (i < 1245184) { src = wq; dst = wqb; off = i - 1048576; }
  else                  { src = wo; dst = wob; off = i - 1245184; }
  float4 v = ((const float4*)src)[off];
  uint2 o; o.x = pk_bf16(v.x, v.y); o.y = pk_bf16(v.z, v.w);
  *(uint2*)&dst[off * 4] = o;
}

// ---------------------------------------------------------------- QKV projection
// v6: COUNTED-VMCNT pipeline (T3+T4). 3 LDS buffers, depth-2 prefetch, ONE raw
//   s_barrier per K-step, per-wave `s_waitcnt vmcnt(2)` (never 0 in main loop):
//   round-10/11 bracketed the bottleneck to the compiler's vmcnt(0) drain at
//   every __syncthreads — loads issued 1 period back never hide their latency.
//   Now step t+1's loads stay in flight across the barrier (2 periods to land).
// Hazards: buffer (t+2)%3 overwritten at period t was last READ at t-1; every
//   wave passed the t-barrier only after finishing t-1's compute -> safe.
//   vmcnt counting: 2 loads/thread/STAGE; prologue 4 outstanding; vmcnt(2) at t
//   retires step-t's pair (in-order); tail t=15 drains 0.
// 128x128 tile, BK=32, 512 thr (8 waves, 4m x 2f, acc[2][4]); LDS 48KB;
// (512,6) -> 3 blocks/CU = 24 waves/CU. Swizzle = round-10 verbatim.
__global__ __launch_bounds__(512, 6) void qkv_gemm(const short* __restrict__ A,
                                                   const short* __restrict__ W,
                                                   const float* __restrict__ bias,
                                                   short* __restrict__ qo,
                                                   short* __restrict__ ko,
                                                   short* __restrict__ vto) {
  __shared__ __align__(16) short As[3][128 * 32];   // 8KB each
  __shared__ __align__(16) short Bs[3][128 * 32];
  const int tid  = threadIdx.x;
  const int lane = tid & 63, wave = tid >> 6;
  const int wm = wave >> 1, wf = wave & 1;
  const int col = lane & 15, quad = lane >> 4;
  const int m0 = blockIdx.x * 128, f0 = blockIdx.y * 128;

  // staging: slot = tid (512 slots = 128 rows x 4 chunks)
  const int row = tid >> 2;
  const int cb  = (tid & 3) ^ ((tid >> 3) & 3);
  const short* aSrc = A + (size_t)(m0 + row) * 512 + cb * 8;
  const short* wSrc = W + (size_t)(f0 + row) * 512 + cb * 8;

  // fragment LDS element offsets (row*32 + readchunk*8)
  const int rc = (quad ^ ((col >> 1) & 3)) * 8;
  int aOff[2], bOff[4];
#pragma unroll
  for (int i = 0; i < 2; ++i) aOff[i] = (wm * 32 + i * 16 + col) * 32 + rc;
#pragma unroll
  for (int j = 0; j < 4; ++j) bOff[j] = (wf * 64 + j * 16 + col) * 32 + rc;

  f32x4 acc[2][4];
#pragma unroll
  for (int i = 0; i < 2; ++i)
#pragma unroll
    for (int j = 0; j < 4; ++j)
#pragma unroll
      for (int r = 0; r < 4; ++r) acc[i][j][r] = 0.f;

#define QSTAGE(BI, KS)                                                \
  {                                                                   \
    gl_lds16(aSrc + (KS) * 32, (char*)As[BI] + wave * 1024);          \
    gl_lds16(wSrc + (KS) * 32, (char*)Bs[BI] + wave * 1024);          \
  }

  auto qcompute = [&](const short* Asb, const short* Bsb) {
    bf16x8 af[2], bw[4];
#pragma unroll
    for (int i = 0; i < 2; ++i) af[i] = *(const bf16x8*)&Asb[aOff[i]];
#pragma unroll
    for (int j = 0; j < 4; ++j) bw[j] = *(const bf16x8*)&Bsb[bOff[j]];
#pragma unroll
    for (int i = 0; i < 2; ++i)
#pragma unroll
      for (int j = 0; j < 4; ++j)
        acc[i][j] = __builtin_amdgcn_mfma_f32_16x16x32_bf16(af[i], bw[j], acc[i][j], 0, 0, 0);
  };

  // prologue: two K-steps in flight
  QSTAGE(0, 0);
  QSTAGE(1, 1);
#pragma unroll
  for (int t = 0; t < 16; ++t) {
    if (t < 15) { asm volatile("s_waitcnt vmcnt(2)" ::: "memory"); }
    else        { asm volatile("s_waitcnt vmcnt(0)" ::: "memory"); }
    __builtin_amdgcn_sched_barrier(0);
    __builtin_amdgcn_s_barrier();
    if (t + 2 < 16) QSTAGE((t + 2) % 3, t + 2);
    qcompute(As[t % 3], Bs[t % 3]);
  }
#undef QSTAGE

  // epilogue: C/D layout row = quad*4+r, col = lane&15
#pragma unroll
  for (int j = 0; j < 4; ++j) {
    const int f = f0 + wf * 64 + j * 16 + col;
    const float bv = bias[f];
    const int sIdx = f >> 9;          // 0=Q 1=K 2=V (uniform per wave: 64-wide span)
    const int h = (f >> 6) & 7;
    const int d = f & 63;
#pragma unroll
    for (int i = 0; i < 2; ++i) {
      const int mbase = m0 + wm * 32 + i * 16 + quad * 4;
      const int b = mbase >> 11;
      const int n = mbase & 2047;
      const size_t bh = (size_t)(b * NH + h);
      if (sIdx == 2) {
        uint2 pk;
        pk.x = pk_bf16(acc[i][j][0] + bv, acc[i][j][1] + bv);
        pk.y = pk_bf16(acc[i][j][2] + bv, acc[i][j][3] + bv);
        *(uint2*)&vto[(bh * HD + d) * SEQ + n] = pk;     // V^T: (bh, d, n)
      } else if (sIdx == 0) {
#pragma unroll
        for (int r = 0; r < 4; ++r)
          qo[(bh * SEQ + n + r) * HD + d] = f2bf((acc[i][j][r] + bv) * QSCALE);
      } else {
#pragma unroll
        for (int r = 0; r < 4; ++r)
          ko[(bh * SEQ + n + r) * HD + d] = f2bf(acc[i][j][r] + bv);
      }
    }
  }
}

// ---------------------------------------------------------------- flash attention v7 (round-4/8/10 best: ~56-58us)
// grid = 512 x 512 threads: bh = blk&31, qtile = blk>>5 (128 q/block, 8 waves x 16 q)
// K,V: double-buffered LDS (XOR-swizzled, global_load_lds), 1 barrier/tile.
// P: in-register redistribution (permlane16/32_swap), no LDS round-trip.
// S^T operand-swap; fixed-max softmax (exp2, scale pre-folded into Q).
__global__ __launch_bounds__(512) void attn_kernel(const short* __restrict__ q,
                                                   const short* __restrict__ k,
                                                   const short* __restrict__ vt,
                                                   short* __restrict__ o) {
  __shared__ __align__(16) short Ks0[64 * 64];       // XOR-swizzled
  __shared__ __align__(16) short Vs0[64 * 64];
  __shared__ __align__(16) short Ks1[64 * 64];
  __shared__ __align__(16) short Vs1[64 * 64];

  const int tid  = threadIdx.x;
  const int lane = tid & 63, wave = tid >> 6;
  const int col = lane & 15, quad = lane >> 4;
  const int bh = blockIdx.x & 31;
  const int q0 = (blockIdx.x >> 5) * 128;
  const size_t bhBase = (size_t)bh * SEQ * HD;

  // Q fragments (B-operand): lane holds Q'[q=col][d = ks*32 + quad*8 + j]
  bf16x8 qf[2];
#pragma unroll
  for (int ks = 0; ks < 2; ++ks)
    qf[ks] = *(const bf16x8*)&q[bhBase +
        (size_t)(q0 + wave * 16 + col) * HD + ks * 32 + quad * 8];

  // staging: 512 threads x 16B = one 64x64 bf16 tile per issue
  const int row = tid >> 3, cb = (tid & 7) ^ (row & 7);
  const short* ksrc = k  + bhBase + (size_t)row * HD  + cb * 8;
  const short* vsrc = vt + bhBase + (size_t)row * SEQ + cb * 8;
  char* const ldsK0 = (char*)Ks0 + wave * 1024;
  char* const ldsV0 = (char*)Vs0 + wave * 1024;
  char* const ldsK1 = (char*)Ks1 + wave * 1024;
  char* const ldsV1 = (char*)Vs1 + wave * 1024;

  f32x4 oacc[4];
#pragma unroll
  for (int nt = 0; nt < 4; ++nt)
#pragma unroll
    for (int r = 0; r < 4; ++r) oacc[nt][r] = 0.f;
  float lsum = 0.f;

  auto compute = [&](const short* KB, const short* VB) {
    // S^T = K Q'^T : C[m=key][n=q]; lane holds S^T[key=kt*16+quad*4+r][q=col]
    f32x4 sacc[4];
#pragma unroll
    for (int kt = 0; kt < 4; ++kt)
#pragma unroll
      for (int r = 0; r < 4; ++r) sacc[kt][r] = 0.f;
#pragma unroll
    for (int ks = 0; ks < 2; ++ks)
#pragma unroll
      for (int kt = 0; kt < 4; ++kt) {
        bf16x8 kf = *(const bf16x8*)&KB[(kt * 16 + col) * 64 +
                                        (((ks * 4 + quad) ^ (col & 7)) * 8)];
        sacc[kt] = __builtin_amdgcn_mfma_f32_16x16x32_bf16(kf, qf[ks], sacc[kt], 0, 0, 0);
      }

    // p = exp2(s') (scale pre-folded into Q'), partial row-sums, pack pairs
    unsigned u[4][2];
#pragma unroll
    for (int kt = 0; kt < 4; ++kt) {
      float p0 = fexp2(sacc[kt][0]);
      float p1 = fexp2(sacc[kt][1]);
      float p2 = fexp2(sacc[kt][2]);
      float p3 = fexp2(sacc[kt][3]);
      lsum += (p0 + p1) + (p2 + p3);
      u[kt][0] = pk_bf16(p0, p1);   // keys kt*16+quad*4+{0,1}
      u[kt][1] = pk_bf16(p2, p3);   // keys kt*16+quad*4+{2,3}
    }

    // in-register quad redistribution -> PV A-fragments
    // pf[ks2] elem j = P[q=col][key = ks2*32 + quad*8 + j]
    union { unsigned w[4]; bf16x8 v; } pf0, pf1;
    {
      unsigned a, b;
      a = u[0][0]; b = u[1][0]; quad_redist(a, b); pf0.w[0] = a; pf0.w[2] = b;
      a = u[0][1]; b = u[1][1]; quad_redist(a, b); pf0.w[1] = a; pf0.w[3] = b;
      a = u[2][0]; b = u[3][0]; quad_redist(a, b); pf1.w[0] = a; pf1.w[2] = b;
      a = u[2][1]; b = u[3][1]; quad_redist(a, b); pf1.w[1] = a; pf1.w[3] = b;
    }

    // O += P V   (A = P[q][key] in registers, B = V^T[d][key] from LDS)
#pragma unroll
    for (int nt = 0; nt < 4; ++nt) {
      bf16x8 vf0 = *(const bf16x8*)&VB[(nt * 16 + col) * 64 +
                                       ((quad ^ (col & 7)) * 8)];
      oacc[nt] = __builtin_amdgcn_mfma_f32_16x16x32_bf16(pf0.v, vf0, oacc[nt], 0, 0, 0);
      bf16x8 vf1 = *(const bf16x8*)&VB[(nt * 16 + col) * 64 +
                                       (((4 + quad) ^ (col & 7)) * 8)];
      oacc[nt] = __builtin_amdgcn_mfma_f32_16x16x32_bf16(pf1.v, vf1, oacc[nt], 0, 0, 0);
    }
  };

  // prologue: stage tile 0
  gl_lds16(ksrc, ldsK0); gl_lds16(vsrc, ldsV0);
  ksrc += 64 * HD; vsrc += 64;
  __syncthreads();

  for (int t = 0; t < 32; t += 2) {
    // stage tile t+1 into buf1; compute tile t from buf0
    gl_lds16(ksrc, ldsK1); gl_lds16(vsrc, ldsV1);
    ksrc += 64 * HD; vsrc += 64;
    compute(Ks0, Vs0);
    __syncthreads();                 // drains t+1 loads (flew during compute)
    // stage tile t+2 into buf0; compute tile t+1 from buf1
    // (final iteration prefetches one tile past the end — lands in the
    //  adjacent workspace arrays, in-bounds of d_ws, never consumed)
    gl_lds16(ksrc, ldsK0); gl_lds16(vsrc, ldsV0);
    ksrc += 64 * HD; vsrc += 64;
    compute(Ks1, Vs1);
    __syncthreads();
  }

  // final row-sum reduce across quads (lanes sharing col hold partials)
  lsum += __shfl_xor(lsum, 16);
  lsum += __shfl_xor(lsum, 32);

  const int b = bh >> 3, h = bh & 7;
#pragma unroll
  for (int r = 0; r < 4; ++r) {
    const float rl = 1.0f / __shfl(lsum, quad * 4 + r);  // sum for q=quad*4+r lives at lane col==q
    const int n = q0 + wave * 16 + quad * 4 + r;
#pragma unroll
    for (int nt = 0; nt < 4; ++nt)
      o[((size_t)(b * SEQ + n)) * EMB + h * HD + nt * 16 + col] = f2bf(oacc[nt][r] * rl);
  }
}

// ---------------------------------------------------------------- out projection
// v6: counted-vmcnt pipeline, same template as qkv v6. 64x128 tile, BK=32,
// 512 thr (8 waves as 2m x 4f, acc[2][2]); 3 buffers, LDS 36KB, 2 blocks/CU.
// A staged by waves 0-3 (1 load/thr), W by all (1 load/thr) -> wave-uniform
// split waitcnt: low waves vmcnt(2)/period, high waves vmcnt(1).
__global__ __launch_bounds__(512, 4) void proj_gemm(const short* __restrict__ A,
                                                    const short* __restrict__ W,
                                                    const float* __restrict__ bias,
                                                    float* __restrict__ out) {
  __shared__ __align__(16) short As[3][64 * 32];    // 4KB each
  __shared__ __align__(16) short Bs[3][128 * 32];   // 8KB each
  const int tid  = threadIdx.x;
  const int lane = tid & 63, wave = tid >> 6;
  const int wm = wave >> 2, wf = wave & 3;
  const int col = lane & 15, quad = lane >> 4;
  const int m0 = blockIdx.x * 64, f0 = blockIdx.y * 128;

  // A staging slot (waves 0-3 only): aslot = tid&255 -> 64 rows x 4 chunks
  const int aslot = tid & 255;
  const int arow = aslot >> 2, acb = (aslot & 3) ^ ((aslot >> 3) & 3);
  const short* aSrc = A + (size_t)(m0 + arow) * 512 + acb * 8;
  // W staging slot (all 8 waves): 128 rows x 4 chunks
  const int wrow = tid >> 2, wcb = (tid & 3) ^ ((tid >> 3) & 3);
  const short* wSrc = W + (size_t)(f0 + wrow) * 512 + wcb * 8;

  const int rc = (quad ^ ((col >> 1) & 3)) * 8;
  int aOff[2], bOff[2];
#pragma unroll
  for (int i = 0; i < 2; ++i) aOff[i] = (wm * 32 + i * 16 + col) * 32 + rc;
#pragma unroll
  for (int j = 0; j < 2; ++j) bOff[j] = (wf * 32 + j * 16 + col) * 32 + rc;

  f32x4 acc[2][2];
#pragma unroll
  for (int i = 0; i < 2; ++i)
#pragma unroll
    for (int j = 0; j < 2; ++j)
#pragma unroll
      for (int r = 0; r < 4; ++r) acc[i][j][r] = 0.f;

#define PSTAGE(BI, KS)                                                \
  {                                                                   \
    if (wave < 4) gl_lds16(aSrc + (KS) * 32, (char*)As[BI] + wave * 1024); \
    gl_lds16(wSrc + (KS) * 32, (char*)Bs[BI] + wave * 1024);          \
  }

  auto pcompute = [&](const short* Asb, const short* Bsb) {
    bf16x8 af[2], bw[2];
#pragma unroll
    for (int i = 0; i < 2; ++i) af[i] = *(const bf16x8*)&Asb[aOff[i]];
#pragma unroll
    for (int j = 0; j < 2; ++j) bw[j] = *(const bf16x8*)&Bsb[bOff[j]];
#pragma unroll
    for (int i = 0; i < 2; ++i)
#pragma unroll
      for (int j = 0; j < 2; ++j)
        acc[i][j] = __builtin_amdgcn_mfma_f32_16x16x32_bf16(af[i], bw[j], acc[i][j], 0, 0, 0);
  };

  // prologue: two K-steps in flight
  PSTAGE(0, 0);
  PSTAGE(1, 1);
#pragma unroll
  for (int t = 0; t < 16; ++t) {
    if (t < 15) {
      if (wave < 4) { asm volatile("s_waitcnt vmcnt(2)" ::: "memory"); }
      else          { asm volatile("s_waitcnt vmcnt(1)" ::: "memory"); }
    } else {
      asm volatile("s_waitcnt vmcnt(0)" ::: "memory");
    }
    __builtin_amdgcn_sched_barrier(0);
    __builtin_amdgcn_s_barrier();
    if (t + 2 < 16) PSTAGE((t + 2) % 3, t + 2);
    pcompute(As[t % 3], Bs[t % 3]);
  }
#undef PSTAGE

#pragma unroll
  for (int j = 0; j < 2; ++j) {
    const int f = f0 + wf * 32 + j * 16 + col;
    const float bv = bias[f];
#pragma unroll
    for (int i = 0; i < 2; ++i) {
      const int mbase = m0 + wm * 32 + i * 16 + quad * 4;
#pragma unroll
      for (int r = 0; r < 4; ++r)
        out[(size_t)(mbase + r) * 512 + f] = acc[i][j][r] + bv;
    }
  }
}

// ---------------------------------------------------------------- launch
extern "C" void kernel_launch(void* const* d_in, const int* in_sizes, int n_in,
                              void* d_out, int out_size, void* d_ws, size_t ws_size,
                              hipStream_t stream) {
  (void)in_sizes; (void)n_in; (void)out_size; (void)ws_size;
  const float* x     = (const float*)d_in[0];
  const float* w_qkv = (const float*)d_in[1];
  const float* b_qkv = (const float*)d_in[2];
  const float* w_out = (const float*)d_in[3];
  const float* b_out = (const float*)d_in[4];
  float* out = (float*)d_out;

  char* ws = (char*)d_ws;
  short* xb    = (short*)(ws + 0);         // 8,388,608
  short* wqkvb = (short*)(ws + 8388608);   // 1,572,864
  short* woutb = (short*)(ws + 9961472);   //   524,288
  short* qb    = (short*)(ws + 10485760);  // 8,388,608  (b,h,n,d)  pre-scaled by QSCALE
  short* kb    = (short*)(ws + 18874368);  // 8,388,608  (b,h,n,d)
  short* vtb   = (short*)(ws + 27262976);  // 8,388,608  (b,h,d,n)
  short* ob    = (short*)(ws + 35651584);  // 8,388,608  (b,n,e)

  cast_all<<<5120, 256, 0, stream>>>(x, w_qkv, w_out, xb, wqkvb, woutb);
  qkv_gemm<<<dim3(64, 12), 512, 0, stream>>>(xb, wqkvb, b_qkv, qb, kb, vtb);
  attn_kernel<<<512, 512, 0, stream>>>(qb, kb, vtb, ob);
  proj_gemm<<<dim3(128, 4), 512, 0, stream>>>(ob, woutb, b_out, out);
}